// Round 7
// baseline (74.509 us; speedup 1.0000x reference)
//
#include <hip/hip_runtime.h>

// Retrace loss: T=8192, K=2048, gamma=0.99.
// decay = cumprod(gamma*iw); S = reverse-cumsum(td*decay);
// retrace = S / max(decay,1e-10); loss = mean(smooth_l1(q, retrace)).
//
// f32 decay underflows to EXACT 0 within ~170 rows for every column
// (E[ln c]=-0.57; at row 512 log-decay = -294 +- ~18 sigma); once decay==0,
// retrace==0 in both our and the reference's arithmetic (absmax 0.0, R6).
//
// R7 structure (R6 was 4 serialized launches; ~30 us of structure):
//  memset : zero 16-byte ctrl (acc,done).
//  kF1    : role P (256 blocks): LDS-tile scan of rows [0,512) -> pk,P,Zl;
//           role T (2048 blocks): unconditional tail sum sl1(sv) rows
//           [512,8191) -- runs CONCURRENTLY with role P in one launch.
//  kF2    : apply with INLINE chunk scan (re-derive D0/Ssuf/alive from
//           P/Zl, L2-hot) + exact fallback for alive columns (corrects
//           the tail-assumed terms; never taken for this data) + last
//           block writes the mean (ticket) -- kScan and k4 eliminated.

#define GAMMA 0.99f

constexpr int T_ = 8192;
constexpr int K_ = 2048;
constexpr int N_ = T_ - 1;               // 8191
constexpr int MROWS = 512;               // exact-prefix length
constexpr int L_ = 16;                   // rows per chunk
constexpr int MCH = MROWS / L_;          // 32 chunks
constexpr int NBPRE = MCH * (K_ / 256);  // 256 role-P blocks
constexpr int NBTAIL = 2048;             // role-T blocks
constexpr long long TAILF4 = (long long)(N_ - MROWS) * K_ / 4;  // 3,931,648

typedef float f4 __attribute__((ext_vector_type(4)));
typedef unsigned short us4 __attribute__((ext_vector_type(4)));

__device__ __forceinline__ unsigned short f2bf(float f) {  // RTNE
  unsigned u = __float_as_uint(f);
  u += 0x7FFFu + ((u >> 16) & 1u);
  return (unsigned short)(u >> 16);
}
__device__ __forceinline__ float bf2f(unsigned short h) {
  return __uint_as_float(((unsigned)h) << 16);
}
__device__ __forceinline__ float bfhi(unsigned q) {  // y in hi16
  return __uint_as_float(q & 0xFFFF0000u);
}
__device__ __forceinline__ float bflo(unsigned q) {  // ld in lo16
  return __uint_as_float(q << 16);
}
__device__ __forceinline__ float sl1(float dd) {
  float ad = fabsf(dd);
  return (ad < 1.f) ? 0.5f * dd * dd : ad - 0.5f;
}
__device__ __forceinline__ void block_reduce_add(float l, double* acc) {
  for (int off = 32; off > 0; off >>= 1) l += __shfl_down(l, off);
  __shared__ float wsum[4];
  const int lane = threadIdx.x & 63, wid = threadIdx.x >> 6;
  if (lane == 0) wsum[wid] = l;
  __syncthreads();
  if (threadIdx.x == 0)
    atomicAdd(acc, (double)(wsum[0] + wsum[1] + wsum[2] + wsum[3]));
}

// ---------------------------------------------------------------- kF1
__global__ __launch_bounds__(256) void kF1(
    const float* __restrict__ sv, const float* __restrict__ tsv,
    const float* __restrict__ tev, const float* __restrict__ r,
    const float* __restrict__ ologp, const float* __restrict__ tlogp,
    unsigned* __restrict__ pkPre, float* __restrict__ P,
    float* __restrict__ Zl, double* __restrict__ acc) {
  const int bid = blockIdx.x;
  const int tid = threadIdx.x;

  if (bid < NBPRE) {  // ---- role P: 16x256 tile of rows [0,512)
    __shared__ float csh[L_][256];            // f32 c (exact chain)
    __shared__ unsigned short tdsh[L_][256];  // bf16 td
    const int lane = tid & 63;
    const int wid = tid >> 6;
    const int c0 = (bid & 7) * 256;
    const int chunk = bid >> 3;
    const int i0 = chunk * L_;
    const int col = c0 + lane * 4;

    // phase 1: wave w handles rows w, w+4, w+8, w+12 (depth-1 pipeline)
    f4 lwA, aA, vA, rrA;
    float oA;
    auto issue = [&](int s, f4& lw, f4& a, f4& v, f4& rr, float& o) {
      const int i = i0 + s;
      const size_t b1 = (size_t)(i + 1) * K_ + col;
      const size_t b0 = (size_t)i * K_ + col;
      lw = *(const f4*)(tlogp + b1);
      a = *(const f4*)(tsv + b1);
      v = *(const f4*)(tev + b1);
      rr = *(const f4*)(r + b0);
      o = ologp[i + 1];
    };
    issue(wid, lwA, aA, vA, rrA, oA);
#pragma unroll
    for (int s0 = 0; s0 < L_; s0 += 4) {
      const int s = s0 + wid;
      f4 lwB, aB, vB, rrB;
      float oB;
      if (s0 + 4 < L_) issue(s + 4, lwB, aB, vB, rrB, oB);
      __builtin_amdgcn_sched_barrier(0);
      f4 iw, c, td;
#pragma unroll
      for (int x = 0; x < 4; ++x) iw[x] = __expf(fminf(lwA[x] - oA, 0.f));
#pragma unroll
      for (int x = 0; x < 4; ++x) c[x] = GAMMA * iw[x];
#pragma unroll
      for (int x = 0; x < 4; ++x)
        td[x] = fmaf(GAMMA, fmaf(-iw[x], aA[x], vA[x]), rrA[x]);
      *(f4*)&csh[s][lane * 4] = c;
      us4 t4;
#pragma unroll
      for (int x = 0; x < 4; ++x) t4[x] = f2bf(td[x]);
      *(us4*)&tdsh[s][lane * 4] = t4;
      if (s0 + 4 < L_) {
        lwA = lwB;
        aA = aB;
        vA = vB;
        rrA = rrB;
        oA = oB;
      }
    }
    __syncthreads();

    // phase 2: per-column f32 chain, store packed y|ld
    const int kcol = c0 + tid;
    float p = 1.f, zl = 0.f;
#pragma unroll
    for (int s = 0; s < L_; ++s) {
      p *= csh[s][tid];
      float y = bf2f(tdsh[s][tid]) * p;
      zl += y;
      pkPre[(size_t)(i0 + s) * K_ + kcol] =
          ((unsigned)f2bf(y) << 16) | f2bf(p);
    }
    P[(size_t)chunk * K_ + kcol] = p;
    Zl[(size_t)chunk * K_ + kcol] = zl;
  } else {  // ---- role T: tail rows [512,8191), all columns
    const long long base = (long long)MROWS * K_ / 4;  // f4 offset
    float loss = 0.f;
    for (long long v = (long long)(bid - NBPRE) * 256 + tid; v < TAILF4;
         v += (long long)NBTAIL * 256) {
      f4 q = ((const f4*)sv)[base + v];
#pragma unroll
      for (int x = 0; x < 4; ++x) loss += sl1(q[x]);
    }
    block_reduce_add(loss, acc);
  }
}

// ---------------------------------------------------------------- kF2
// Block b: chunk = b>>3, columns (b&7)*256 + tid. Inline scan over the
// 32 chunk summaries (P/Zl are 256 KB: L2-hot), then apply; alive columns
// (full-prefix product != 0) go through the exact serial fallback once
// (chunk-0 block), subtracting the tail terms kF1 assumed. Last block
// writes the mean.
__global__ __launch_bounds__(256) void kF2(
    const float* __restrict__ sv, const float* __restrict__ tsv,
    const float* __restrict__ tev, const float* __restrict__ r,
    const float* __restrict__ ologp, const float* __restrict__ tlogp,
    const unsigned* __restrict__ pkPre, const float* __restrict__ P,
    const float* __restrict__ Zl, unsigned* __restrict__ pkFull,
    double* __restrict__ acc, unsigned* __restrict__ done,
    float* __restrict__ out) {
  const int bid = blockIdx.x;
  const int tid = threadIdx.x;
  const int myc = bid >> 3;
  const int k = (bid & 7) * 256 + tid;

  // inline scan: d0 = prod_{c<myc} P_c; total product (alive test)
  float d0 = 1.f, dj = 1.f;
#pragma unroll
  for (int c = 0; c < MCH; ++c) {
    if (c == myc) d0 = dj;
    dj *= P[(size_t)c * K_ + k];
  }
  const bool alive = (dj != 0.f);
  // ssuf = sum_{c>myc} D0_c * Zl_c
  float ssuf = 0.f;
  float dp = d0 * P[(size_t)myc * K_ + k];
  for (int c = myc + 1; c < MCH; ++c) {
    ssuf = fmaf(dp, Zl[(size_t)c * K_ + k], ssuf);
    dp *= P[(size_t)c * K_ + k];
  }

  float loss = 0.f;
  if (!alive) {
    const int i0 = myc * L_;
    float slocal = 0.f;
#pragma unroll
    for (int s = L_ - 1; s >= 0; --s) {
      const size_t b0 = (size_t)(i0 + s) * K_ + k;
      unsigned q = pkPre[b0];
      slocal += bfhi(q);
      float S = fmaf(d0, slocal, ssuf);
      float retrace = S / fmaxf(d0 * bflo(q), 1e-10f);
      loss += sl1(sv[b0] - retrace);
    }
  } else if (myc == 0) {  // exact fallback (never taken for this data)
    unsigned* mycol = pkFull + (size_t)k * 8192;
    float p = 1.f;
    for (int i = 0; i < N_; ++i) {  // forward: exact sequential decay
      const size_t b1 = (size_t)(i + 1) * K_ + k;
      float iw = __expf(fminf(tlogp[b1] - ologp[i + 1], 0.f));
      p *= GAMMA * iw;
      float td =
          fmaf(GAMMA, fmaf(-iw, tsv[b1], tev[b1]), r[(size_t)i * K_ + k]);
      mycol[i] = ((unsigned)f2bf(td * p) << 16) | f2bf(p);
    }
    float slocal = 0.f;
    for (int i = N_ - 1; i >= 0; --i) {  // backward: S, loss, tail undo
      unsigned q = mycol[i];
      slocal += bfhi(q);
      float retrace = slocal / fmaxf(bflo(q), 1e-10f);
      float qv = sv[(size_t)i * K_ + k];
      loss += sl1(qv - retrace);
      if (i >= MROWS) loss -= sl1(qv);  // kF1 role T already added this
    }
  }
  block_reduce_add(loss, acc);

  // ticket: last block publishes the mean
  __threadfence();
  if (tid == 0) {
    const unsigned prev = atomicAdd(done, 1u);
    if (prev == gridDim.x - 1) {
      __threadfence();
      out[0] = (float)(*acc * (1.0 / ((double)N_ * (double)K_)));
    }
  }
}

extern "C" void kernel_launch(void* const* d_in, const int* in_sizes, int n_in,
                              void* d_out, int out_size, void* d_ws,
                              size_t ws_size, hipStream_t stream) {
  const float* sv = (const float*)d_in[0];
  const float* tsv = (const float*)d_in[1];
  const float* tev = (const float*)d_in[2];
  const float* r = (const float*)d_in[3];
  const float* ologp = (const float*)d_in[4];
  const float* tlogp = (const float*)d_in[5];

  // ws layout (~71.6 MB; harness provides well above this, proven R2-R6)
  char* w = (char*)d_ws;
  double* acc = (double*)w;        // ctrl block: acc(8) + done(4)
  unsigned* done = (unsigned*)(w + 8);
  w += 256;
  unsigned* pkPre = (unsigned*)w;  // 512*2048*4 = 4 MB
  w += (size_t)MROWS * K_ * 4;
  float* P = (float*)w;            // 32*2048*4 = 256 KB
  w += (size_t)MCH * K_ * 4;
  float* Zl = (float*)w;
  w += (size_t)MCH * K_ * 4;
  unsigned* pkFull = (unsigned*)w; // 2048*8192*4 = 67 MB (fallback only)

  hipMemsetAsync(d_ws, 0, 16, stream);  // zero acc + done (capture-safe)
  kF1<<<NBPRE + NBTAIL, 256, 0, stream>>>(sv, tsv, tev, r, ologp, tlogp,
                                          pkPre, P, Zl, acc);
  kF2<<<NBPRE, 256, 0, stream>>>(sv, tsv, tev, r, ologp, tlogp, pkPre, P, Zl,
                                 pkFull, acc, done, (float*)d_out);
}